// Round 1
// baseline (614.179 us; speedup 1.0000x reference)
//
#include <hip/hip_runtime.h>
#include <hip/hip_bf16.h>
#include <cstdint>
#include <cmath>

#define S_LEN 4096
#define DMODEL 2048
#define NH 16
#define NKV 4
#define HD 128
#define NQKV 3072  // 2048 Q + 512 K + 512 V

typedef unsigned short u16;
typedef __attribute__((ext_vector_type(8))) __bf16 bf16x8;
typedef __attribute__((ext_vector_type(4))) float f32x4;

__device__ __forceinline__ u16 f2bf(float f) {
  __bf16 h = (__bf16)f;  // RNE
  return __builtin_bit_cast(u16, h);
}
__device__ __forceinline__ float bf2f(u16 u) {
  return (float)__builtin_bit_cast(__bf16, u);
}

__device__ __forceinline__ void gload16(const void* g, void* l) {
  __builtin_amdgcn_global_load_lds(
      (const __attribute__((address_space(1))) void*)g,
      (__attribute__((address_space(3))) void*)l, 16, 0, 0);
}

// ---------------- pack / convert ----------------
__global__ void k_f32_to_bf16(const float* __restrict__ src, u16* __restrict__ dst, int n4) {
  int i = blockIdx.x * blockDim.x + threadIdx.x;
  if (i < n4) {
    float4 v = reinterpret_cast<const float4*>(src)[i];
    ushort4 o = make_ushort4(f2bf(v.x), f2bf(v.y), f2bf(v.z), f2bf(v.w));
    reinterpret_cast<ushort4*>(dst)[i] = o;
  }
}

// dst[n][k] = bf16(src[k][n]); src row stride srcStride, dst row stride dstStride
__global__ void k_transpose_f32_bf16(const float* __restrict__ src, int srcStride,
                                     u16* __restrict__ dst, int dstStride) {
  __shared__ float tile[32][33];
  int n0 = blockIdx.x * 32, k0 = blockIdx.y * 32;
  int tx = threadIdx.x, ty = threadIdx.y;  // 32 x 8
#pragma unroll
  for (int r = 0; r < 32; r += 8)
    tile[ty + r][tx] = src[(size_t)(k0 + ty + r) * srcStride + n0 + tx];
  __syncthreads();
#pragma unroll
  for (int r = 0; r < 32; r += 8)
    dst[(size_t)(n0 + ty + r) * dstStride + k0 + tx] = f2bf(tile[tx][ty + r]);
}

__global__ void k_transpose_bf16(const u16* __restrict__ src, int srcStride,
                                 u16* __restrict__ dst, int dstStride) {
  __shared__ u16 tile[32][33];
  int n0 = blockIdx.x * 32, k0 = blockIdx.y * 32;
  int tx = threadIdx.x, ty = threadIdx.y;  // 32 x 8
#pragma unroll
  for (int r = 0; r < 32; r += 8)
    tile[ty + r][tx] = src[(size_t)(k0 + ty + r) * srcStride + n0 + tx];
  __syncthreads();
#pragma unroll
  for (int r = 0; r < 32; r += 8)
    dst[(size_t)(n0 + ty + r) * dstStride + k0 + tx] = tile[tx][ty + r];
}

// ---------------- RoPE (+fold 1/sqrt(HD) into Q) ----------------
__global__ void k_rope(const u16* __restrict__ qkv, const int* __restrict__ pos_ids,
                       u16* __restrict__ Qb, u16* __restrict__ Kb) {
  int s = blockIdx.x;
  float pos = (float)pos_ids[s];
  const u16* row = qkv + (size_t)s * NQKV;
  const float L2B = 13.287712379549449f;  // log2(10000)
  for (int c = threadIdx.x; c < DMODEL + NKV * HD; c += blockDim.x) {
    int d = c & 127;
    int dh = d & 63;
    float invf = exp2f(-(float)dh * (L2B / 64.0f));
    float ang = pos * invf;
    float cv = cosf(ang), sv = sinf(ang);
    float x = bf2f(row[c]);
    float xp = bf2f(row[c ^ 64]);
    float rot = (d < 64) ? -xp : xp;
    float out = x * cv + rot * sv;
    if (c < DMODEL) {
      int h = c >> 7;
      out *= 0.08838834764831845f;  // 1/sqrt(128)
      Qb[((size_t)h * S_LEN + s) * HD + d] = f2bf(out);
    } else {
      int kvh = (c - DMODEL) >> 7;
      Kb[((size_t)kvh * S_LEN + s) * HD + d] = f2bf(out);
    }
  }
}

// ---------------- m97-style 128x128 GEMM, B^T operand ----------------
// C[M][N] = A[M][K] @ BT[N][K]^T    (A,BT bf16; C f32 or bf16)
template <int OUT_BF16>
__global__ __launch_bounds__(256) void k_gemm_bt(const u16* __restrict__ A,
                                                 const u16* __restrict__ BT,
                                                 void* __restrict__ C, int M, int N, int K) {
  __shared__ __align__(16) u16 As[128 * 32];
  __shared__ __align__(16) u16 Bs[128 * 32];
  const int tid = threadIdx.x, wave = tid >> 6, lane = tid & 63;
  const int fr = lane & 15, fq = lane >> 4;
  const int rowBase = blockIdx.y * 128, colBase = blockIdx.x * 128;
  const int wr = wave >> 1, wc = wave & 1;
  f32x4 acc[4][4] = {};
  const int nk = K >> 5;
  for (int kt = 0; kt < nk; ++kt) {
    const int k0 = kt << 5;
#pragma unroll
    for (int p = 0; p < 2; ++p) {
      int cbase = p * 256 + wave * 64;
      int chunk = cbase + lane;
      int r = chunk >> 2, cb = chunk & 3;
      gload16(A + (size_t)(rowBase + r) * K + k0 + cb * 8, (char*)As + cbase * 16);
      gload16(BT + (size_t)(colBase + r) * K + k0 + cb * 8, (char*)Bs + cbase * 16);
    }
    __syncthreads();
    bf16x8 a[4], b[4];
#pragma unroll
    for (int m = 0; m < 4; ++m)
      a[m] = *reinterpret_cast<const bf16x8*>(&As[(wr * 64 + m * 16 + fr) * 32 + fq * 8]);
#pragma unroll
    for (int n = 0; n < 4; ++n)
      b[n] = *reinterpret_cast<const bf16x8*>(&Bs[(wc * 64 + n * 16 + fr) * 32 + fq * 8]);
#pragma unroll
    for (int m = 0; m < 4; ++m)
#pragma unroll
      for (int n = 0; n < 4; ++n)
        acc[m][n] = __builtin_amdgcn_mfma_f32_16x16x32_bf16(a[m], b[n], acc[m][n], 0, 0, 0);
    __syncthreads();
  }
#pragma unroll
  for (int m = 0; m < 4; ++m) {
    int row0 = rowBase + wr * 64 + m * 16 + fq * 4;
#pragma unroll
    for (int n = 0; n < 4; ++n) {
      int col = colBase + wc * 64 + n * 16 + fr;
#pragma unroll
      for (int j = 0; j < 4; ++j) {
        if (OUT_BF16)
          ((u16*)C)[(size_t)(row0 + j) * N + col] = f2bf(acc[m][n][j]);
        else
          ((float*)C)[(size_t)(row0 + j) * N + col] = acc[m][n][j];
      }
    }
  }
}

// ---------------- flash attention (causal, GQA) ----------------
// Qb [H][S][HD] (pre-scaled), Kb [KV][S][HD], VT [KV][HD][S], AO [S][H*HD]
__global__ __launch_bounds__(256) void k_attn(const u16* __restrict__ Qb,
                                              const u16* __restrict__ Kb,
                                              const u16* __restrict__ VT,
                                              u16* __restrict__ AO) {
  __shared__ __align__(16) u16 Ks[64 * 128];   // [k][d], XOR-swizzled
  __shared__ __align__(16) u16 Vs[128 * 64];   // [d][k], XOR-swizzled
  __shared__ __align__(16) u16 Ps[4][16 * 64]; // per-wave P, XOR-swizzled
  const int qt = blockIdx.x, h = blockIdx.y, kv = h >> 2;
  const int tid = threadIdx.x, wave = tid >> 6, lane = tid & 63;
  const int fr = lane & 15, fq = lane >> 4;
  const int qrow0 = qt * 64;
  const float LOG2E = 1.4426950408889634f;

  // Q fragments (A operand), rows = this wave's 16-row band
  bf16x8 qf[4];
  {
    const u16* qp = Qb + ((size_t)h * S_LEN + qrow0 + wave * 16 + fr) * HD;
#pragma unroll
    for (int t = 0; t < 4; ++t)
      qf[t] = *reinterpret_cast<const bf16x8*>(qp + t * 32 + fq * 8);
  }
  f32x4 o[8] = {};
  float mrow[4], lrow[4];
#pragma unroll
  for (int j = 0; j < 4; ++j) { mrow[j] = -INFINITY; lrow[j] = 0.f; }

  const int nkt = qt + 1;
  for (int kt = 0; kt < nkt; ++kt) {
    const int kb = kt * 64;
    // stage K [64][128] and VT [128][64]; pre-swizzled global source (T2/G21)
#pragma unroll
    for (int p = 0; p < 4; ++p) {
      int cbase = p * 256 + wave * 64;
      int chunk = cbase + lane;
      int r = chunk >> 4, cb = chunk & 15;
      int cbs = cb ^ (r & 7);
      gload16(Kb + ((size_t)kv * S_LEN + kb + r) * HD + cbs * 8, (char*)Ks + cbase * 16);
      int d = chunk >> 3, vb = chunk & 7;
      int vbs = vb ^ (d & 7);
      gload16(VT + ((size_t)kv * HD + d) * S_LEN + kb + vbs * 8, (char*)Vs + cbase * 16);
    }
    __syncthreads();

    // S = Q K^T  (16q x 64k per wave)
    f32x4 sa[4] = {};
#pragma unroll
    for (int n = 0; n < 4; ++n) {
      int kr = n * 16 + fr;
#pragma unroll
      for (int t = 0; t < 4; ++t) {
        int byte = (kr * 256 + (t * 32 + fq * 8) * 2) ^ ((kr & 7) << 4);
        bf16x8 kf = *reinterpret_cast<const bf16x8*>((const char*)Ks + byte);
        sa[n] = __builtin_amdgcn_mfma_f32_16x16x32_bf16(qf[t], kf, sa[n], 0, 0, 0);
      }
    }
    // causal mask on the diagonal tile
    if (kt == qt) {
#pragma unroll
      for (int n = 0; n < 4; ++n) {
        int kg = kb + n * 16 + fr;
#pragma unroll
        for (int j = 0; j < 4; ++j) {
          int qg = qrow0 + wave * 16 + fq * 4 + j;
          if (kg > qg) sa[n][j] = -1e30f;
        }
      }
    }
    // online softmax (rows live across 16 lanes of the fr-group)
    float corr[4];
#pragma unroll
    for (int j = 0; j < 4; ++j) {
      float v = fmaxf(fmaxf(sa[0][j], sa[1][j]), fmaxf(sa[2][j], sa[3][j]));
#pragma unroll
      for (int w = 1; w < 16; w <<= 1) v = fmaxf(v, __shfl_xor(v, w));
      float mn = fmaxf(mrow[j], v);
      corr[j] = exp2f((mrow[j] - mn) * LOG2E);
      mrow[j] = mn;
    }
    float rs[4] = {0.f, 0.f, 0.f, 0.f};
#pragma unroll
    for (int n = 0; n < 4; ++n)
#pragma unroll
      for (int j = 0; j < 4; ++j) {
        float p = exp2f((sa[n][j] - mrow[j]) * LOG2E);
        sa[n][j] = p;
        rs[j] += p;
      }
#pragma unroll
    for (int j = 0; j < 4; ++j) {
      float v = rs[j];
#pragma unroll
      for (int w = 1; w < 16; w <<= 1) v += __shfl_xor(v, w);
      lrow[j] = lrow[j] * corr[j] + v;
    }
#pragma unroll
    for (int nd = 0; nd < 8; ++nd)
#pragma unroll
      for (int j = 0; j < 4; ++j) o[nd][j] *= corr[j];

    // P -> LDS (bf16, swizzled), becomes PV A-operand
    char* pw = (char*)Ps[wave];
#pragma unroll
    for (int n = 0; n < 4; ++n)
#pragma unroll
      for (int j = 0; j < 4; ++j) {
        int q = fq * 4 + j;
        int byte = (q * 128 + (n * 16 + fr) * 2) ^ ((q & 7) << 4);
        *(u16*)(pw + byte) = f2bf(sa[n][j]);
      }
    asm volatile("s_waitcnt lgkmcnt(0)" ::: "memory");
    bf16x8 pa[2];
#pragma unroll
    for (int t = 0; t < 2; ++t) {
      int byte = (fr * 128 + (t * 32 + fq * 8) * 2) ^ ((fr & 7) << 4);
      pa[t] = *reinterpret_cast<const bf16x8*>(pw + byte);
    }
#pragma unroll
    for (int nd = 0; nd < 8; ++nd) {
      int dr = nd * 16 + fr;
#pragma unroll
      for (int t = 0; t < 2; ++t) {
        int byte = (dr * 128 + (t * 32 + fq * 8) * 2) ^ ((dr & 7) << 4);
        bf16x8 vf = *reinterpret_cast<const bf16x8*>((const char*)Vs + byte);
        o[nd] = __builtin_amdgcn_mfma_f32_16x16x32_bf16(pa[t], vf, o[nd], 0, 0, 0);
      }
    }
    __syncthreads();
  }
  // epilogue: normalize and store AO[s][h*HD + d]
#pragma unroll
  for (int j = 0; j < 4; ++j) {
    float inv = 1.0f / lrow[j];
    int s = qrow0 + wave * 16 + fq * 4 + j;
#pragma unroll
    for (int nd = 0; nd < 8; ++nd)
      AO[(size_t)s * DMODEL + h * HD + nd * 16 + fr] = f2bf(o[nd][j] * inv);
  }
}

// ---------------- launch ----------------
extern "C" void kernel_launch(void* const* d_in, const int* in_sizes, int n_in,
                              void* d_out, int out_size, void* d_ws, size_t ws_size,
                              hipStream_t stream) {
  const float* hidden = (const float*)d_in[0];
  const float* Wq = (const float*)d_in[1];
  const float* Wk = (const float*)d_in[2];
  const float* Wv = (const float*)d_in[3];
  const float* Wo = (const float*)d_in[4];
  // d_in[5] = attention_mask: causal, applied analytically (unused)
  const int* pos_ids = (const int*)d_in[6];
  float* out = (float*)d_out;

  char* ws = (char*)d_ws;
  u16* Xb   = (u16*)(ws);                               // [4096][2048]   16MB
  u16* Wt   = (u16*)(ws + (16ull << 20));               // [3072][2048]   12MB (Wq^T|Wk^T|Wv^T)
  u16* WoT  = (u16*)(ws + (28ull << 20));               // [2048][2048]    8MB
  u16* QKVb = (u16*)(ws + (36ull << 20));               // [4096][3072]   24MB
  u16* Qb   = (u16*)(ws + (60ull << 20));               // [16][4096][128] 16MB
  u16* Kb   = (u16*)(ws + (76ull << 20));               // [4][4096][128]   4MB
  u16* VT   = (u16*)(ws + (80ull << 20));               // [4][128][4096]   4MB
  u16* AO   = QKVb;  // alias: QKVb fully consumed before attention writes AO

  dim3 tb(32, 8);
  k_f32_to_bf16<<<dim3((S_LEN * DMODEL / 4) / 256), dim3(256), 0, stream>>>(
      hidden, Xb, S_LEN * DMODEL / 4);
  k_transpose_f32_bf16<<<dim3(64, 64), tb, 0, stream>>>(Wq, 2048, Wt, 2048);
  k_transpose_f32_bf16<<<dim3(16, 64), tb, 0, stream>>>(Wk, 512, Wt + (size_t)2048 * 2048, 2048);
  k_transpose_f32_bf16<<<dim3(16, 64), tb, 0, stream>>>(Wv, 512, Wt + (size_t)2560 * 2048, 2048);
  k_transpose_f32_bf16<<<dim3(64, 64), tb, 0, stream>>>(Wo, 2048, WoT, 2048);

  k_gemm_bt<1><<<dim3(24, 32), 256, 0, stream>>>(Xb, Wt, QKVb, S_LEN, NQKV, DMODEL);

  k_rope<<<dim3(S_LEN), 256, 0, stream>>>(QKVb, pos_ids, Qb, Kb);
  k_transpose_bf16<<<dim3(16, 128), tb, 0, stream>>>(QKVb + 2560, NQKV, VT, S_LEN);

  k_attn<<<dim3(S_LEN / 64, NH), 256, 0, stream>>>(Qb, Kb, VT, AO);

  k_gemm_bt<0><<<dim3(16, 32), 256, 0, stream>>>(AO, WoT, out, S_LEN, DMODEL, DMODEL);
}

// Round 2
// 433.049 us; speedup vs baseline: 1.4183x; 1.4183x over previous
//
#include <hip/hip_runtime.h>
#include <hip/hip_bf16.h>
#include <cstdint>
#include <cmath>

#define S_LEN 4096
#define DMODEL 2048
#define NH 16
#define NKV 4
#define HD 128
#define NQKV 3072  // 2048 Q + 512 K + 512 V

typedef unsigned short u16;
typedef __attribute__((ext_vector_type(8))) __bf16 bf16x8;
typedef __attribute__((ext_vector_type(4))) float f32x4;

__device__ __forceinline__ u16 f2bf(float f) {
  __bf16 h = (__bf16)f;  // RNE
  return __builtin_bit_cast(u16, h);
}
__device__ __forceinline__ float bf2f(u16 u) {
  return (float)__builtin_bit_cast(__bf16, u);
}

__device__ __forceinline__ void gload16(const void* g, void* l) {
  __builtin_amdgcn_global_load_lds(
      (const __attribute__((address_space(1))) void*)g,
      (__attribute__((address_space(3))) void*)l, 16, 0, 0);
}

// DPP rotation within 16-lane rows: VALU-only cross-lane reduce (no LDS pipe).
template <int CTRL>
__device__ __forceinline__ float dppf(float x) {
  int xi = __builtin_bit_cast(int, x);
  int r = __builtin_amdgcn_update_dpp(xi, xi, CTRL, 0xF, 0xF, true);
  return __builtin_bit_cast(float, r);
}
__device__ __forceinline__ float rmax16(float v) {
  v = fmaxf(v, dppf<0x128>(v));  // row_ror:8
  v = fmaxf(v, dppf<0x124>(v));  // row_ror:4
  v = fmaxf(v, dppf<0x122>(v));  // row_ror:2
  v = fmaxf(v, dppf<0x121>(v));  // row_ror:1
  return v;
}
__device__ __forceinline__ float rsum16(float v) {
  v += dppf<0x128>(v);
  v += dppf<0x124>(v);
  v += dppf<0x122>(v);
  v += dppf<0x121>(v);
  return v;
}

// ---------------- pack / convert ----------------
__global__ void k_f32_to_bf16(const float* __restrict__ src, u16* __restrict__ dst, int n4) {
  int i = blockIdx.x * blockDim.x + threadIdx.x;
  if (i < n4) {
    float4 v = reinterpret_cast<const float4*>(src)[i];
    ushort4 o = make_ushort4(f2bf(v.x), f2bf(v.y), f2bf(v.z), f2bf(v.w));
    reinterpret_cast<ushort4*>(dst)[i] = o;
  }
}

// dst[n][k] = bf16(src[k][n])
__global__ void k_transpose_f32_bf16(const float* __restrict__ src, int srcStride,
                                     u16* __restrict__ dst, int dstStride) {
  __shared__ float tile[32][33];
  int n0 = blockIdx.x * 32, k0 = blockIdx.y * 32;
  int tx = threadIdx.x, ty = threadIdx.y;  // 32 x 8
#pragma unroll
  for (int r = 0; r < 32; r += 8)
    tile[ty + r][tx] = src[(size_t)(k0 + ty + r) * srcStride + n0 + tx];
  __syncthreads();
#pragma unroll
  for (int r = 0; r < 32; r += 8)
    dst[(size_t)(n0 + ty + r) * dstStride + k0 + tx] = f2bf(tile[tx][ty + r]);
}

__global__ void k_transpose_bf16(const u16* __restrict__ src, int srcStride,
                                 u16* __restrict__ dst, int dstStride) {
  __shared__ u16 tile[32][33];
  int n0 = blockIdx.x * 32, k0 = blockIdx.y * 32;
  int tx = threadIdx.x, ty = threadIdx.y;  // 32 x 8
#pragma unroll
  for (int r = 0; r < 32; r += 8)
    tile[ty + r][tx] = src[(size_t)(k0 + ty + r) * srcStride + n0 + tx];
  __syncthreads();
#pragma unroll
  for (int r = 0; r < 32; r += 8)
    dst[(size_t)(n0 + ty + r) * dstStride + k0 + tx] = tile[tx][ty + r];
}

// ---------------- RoPE (+fold 1/sqrt(HD) into Q) ----------------
__global__ void k_rope(const u16* __restrict__ qkv, const int* __restrict__ pos_ids,
                       u16* __restrict__ Qb, u16* __restrict__ Kb) {
  int s = blockIdx.x;
  float pos = (float)pos_ids[s];
  const u16* row = qkv + (size_t)s * NQKV;
  const float L2B = 13.287712379549449f;  // log2(10000)
  for (int c = threadIdx.x; c < DMODEL + NKV * HD; c += blockDim.x) {
    int d = c & 127;
    int dh = d & 63;
    float invf = exp2f(-(float)dh * (L2B / 64.0f));
    float ang = pos * invf;
    float cv = cosf(ang), sv = sinf(ang);
    float x = bf2f(row[c]);
    float xp = bf2f(row[c ^ 64]);
    float rot = (d < 64) ? -xp : xp;
    float out = x * cv + rot * sv;
    if (c < DMODEL) {
      int h = c >> 7;
      out *= 0.08838834764831845f;  // 1/sqrt(128)
      Qb[((size_t)h * S_LEN + s) * HD + d] = f2bf(out);
    } else {
      int kvh = (c - DMODEL) >> 7;
      Kb[((size_t)kvh * S_LEN + s) * HD + d] = f2bf(out);
    }
  }
}

// ---------------- m97-style 128x128 GEMM, B^T operand ----------------
template <int OUT_BF16>
__global__ __launch_bounds__(256) void k_gemm_bt(const u16* __restrict__ A,
                                                 const u16* __restrict__ BT,
                                                 void* __restrict__ C, int M, int N, int K) {
  __shared__ __align__(16) u16 As[128 * 32];
  __shared__ __align__(16) u16 Bs[128 * 32];
  const int tid = threadIdx.x, wave = tid >> 6, lane = tid & 63;
  const int fr = lane & 15, fq = lane >> 4;
  const int rowBase = blockIdx.y * 128, colBase = blockIdx.x * 128;
  const int wr = wave >> 1, wc = wave & 1;
  f32x4 acc[4][4] = {};
  const int nk = K >> 5;
  for (int kt = 0; kt < nk; ++kt) {
    const int k0 = kt << 5;
#pragma unroll
    for (int p = 0; p < 2; ++p) {
      int cbase = p * 256 + wave * 64;
      int chunk = cbase + lane;
      int r = chunk >> 2, cb = chunk & 3;
      gload16(A + (size_t)(rowBase + r) * K + k0 + cb * 8, (char*)As + cbase * 16);
      gload16(BT + (size_t)(colBase + r) * K + k0 + cb * 8, (char*)Bs + cbase * 16);
    }
    __syncthreads();
    bf16x8 a[4], b[4];
#pragma unroll
    for (int m = 0; m < 4; ++m)
      a[m] = *reinterpret_cast<const bf16x8*>(&As[(wr * 64 + m * 16 + fr) * 32 + fq * 8]);
#pragma unroll
    for (int n = 0; n < 4; ++n)
      b[n] = *reinterpret_cast<const bf16x8*>(&Bs[(wc * 64 + n * 16 + fr) * 32 + fq * 8]);
#pragma unroll
    for (int m = 0; m < 4; ++m)
#pragma unroll
      for (int n = 0; n < 4; ++n)
        acc[m][n] = __builtin_amdgcn_mfma_f32_16x16x32_bf16(a[m], b[n], acc[m][n], 0, 0, 0);
    __syncthreads();
  }
#pragma unroll
  for (int m = 0; m < 4; ++m) {
    int row0 = rowBase + wr * 64 + m * 16 + fq * 4;
#pragma unroll
    for (int n = 0; n < 4; ++n) {
      int col = colBase + wc * 64 + n * 16 + fr;
#pragma unroll
      for (int j = 0; j < 4; ++j) {
        if (OUT_BF16)
          ((u16*)C)[(size_t)(row0 + j) * N + col] = f2bf(acc[m][n][j]);
        else
          ((float*)C)[(size_t)(row0 + j) * N + col] = acc[m][n][j];
      }
    }
  }
}

// ---------------- flash attention (causal, GQA) ----------------
// QBLK=128 (4 waves x 32 q-rows), KT=64, double-buffered K/V staging.
// Qb [H][S][HD] (pre-scaled), Kb [KV][S][HD], VT [KV][HD][S], AO [S][H*HD]
__device__ __forceinline__ void stage_kv(const u16* __restrict__ Kbk,
                                         const u16* __restrict__ VTk, int kb,
                                         char* KsB, char* VsB, int wave, int lane) {
#pragma unroll
  for (int p = 0; p < 4; ++p) {
    int cbase = p * 256 + wave * 64;
    int chunk = cbase + lane;
    int r = chunk >> 4, cb = chunk & 15;
    int cbs = cb ^ (r & 7);  // pre-swizzled source -> linear LDS dest (G21)
    gload16(Kbk + (size_t)(kb + r) * HD + cbs * 8, KsB + cbase * 16);
    int d = chunk >> 3, vb = chunk & 7;
    int vbs = vb ^ (d & 7);
    gload16(VTk + (size_t)d * S_LEN + kb + vbs * 8, VsB + cbase * 16);
  }
}

__global__ __launch_bounds__(256) void k_attn(const u16* __restrict__ Qb,
                                              const u16* __restrict__ Kb,
                                              const u16* __restrict__ VT,
                                              u16* __restrict__ AO) {
  __shared__ __align__(16) u16 Ks[2][64 * 128];  // [k][d], XOR-swizzled, dbuf
  __shared__ __align__(16) u16 Vs[2][128 * 64];  // [d][k], XOR-swizzled, dbuf
  __shared__ __align__(16) u16 Ps[128 * 64];     // [q][k], XOR-swizzled
  const int h = blockIdx.x;
  const int qidx = blockIdx.y;
  // complementary-work pairing: blocks bid and bid+256 co-reside on one CU
  // under round-robin dispatch; qt(i) + qt(i+16) = 31 -> ~equal work per CU.
  const int qt = (qidx < 16) ? (31 - qidx) : (qidx - 16);
  const int kv = h >> 2;
  const int tid = threadIdx.x, wave = tid >> 6, lane = tid & 63;
  const int fr = lane & 15, fq = lane >> 4;
  const int qrow0 = qt * 128;
  const int bandq0 = wave * 32;
  const float LOG2E = 1.4426950408889634f;

  const u16* Kbk = Kb + (size_t)kv * S_LEN * HD;
  const u16* VTk = VT + (size_t)kv * HD * S_LEN;

  // prologue: stage tile 0, then load Q frags (overlaps global latency)
  int buf = 0;
  stage_kv(Kbk, VTk, 0, (char*)Ks[0], (char*)Vs[0], wave, lane);

  bf16x8 qf[2][4];
#pragma unroll
  for (int b = 0; b < 2; ++b) {
    const u16* qp = Qb + ((size_t)h * S_LEN + qrow0 + bandq0 + b * 16 + fr) * HD;
#pragma unroll
    for (int t = 0; t < 4; ++t) qf[b][t] = *reinterpret_cast<const bf16x8*>(qp + t * 32 + fq * 8);
  }
  f32x4 o[2][8] = {};
  float mrow[2][4], lrow[2][4];
#pragma unroll
  for (int b = 0; b < 2; ++b)
#pragma unroll
    for (int j = 0; j < 4; ++j) { mrow[b][j] = -INFINITY; lrow[b][j] = 0.f; }

  __syncthreads();  // drains vmcnt: tile 0 + Q frags ready

  const int nkt = 2 * qt + 2;
  for (int kt = 0; kt < nkt; ++kt) {
    if (kt + 1 < nkt)  // T3 2-phase: issue next tile before computing current
      stage_kv(Kbk, VTk, (kt + 1) * 64, (char*)Ks[buf ^ 1], (char*)Vs[buf ^ 1], wave, lane);
    const char* Kc = (const char*)Ks[buf];
    const char* Vc = (const char*)Vs[buf];
    const int kb = kt * 64;

    // S = Q K^T : K frags read once, reused across both 16-row q-bands
    f32x4 sa[2][4] = {};
#pragma unroll
    for (int n = 0; n < 4; ++n) {
      const int kr = n * 16 + fr;
      const int sw = (kr & 7) << 4;
      bf16x8 kf[4];
#pragma unroll
      for (int t = 0; t < 4; ++t)
        kf[t] = *reinterpret_cast<const bf16x8*>(Kc + ((kr * 256 + (t * 32 + fq * 8) * 2) ^ sw));
#pragma unroll
      for (int b = 0; b < 2; ++b)
#pragma unroll
        for (int t = 0; t < 4; ++t)
          sa[b][n] = __builtin_amdgcn_mfma_f32_16x16x32_bf16(qf[b][t], kf[t], sa[b][n], 0, 0, 0);
    }

    // per band: causal mask, online softmax (DPP reduce), rescale O, write P
#pragma unroll
    for (int b = 0; b < 2; ++b) {
      const int qg0 = qrow0 + bandq0 + b * 16;
      if (kb + 63 > qg0) {
#pragma unroll
        for (int n = 0; n < 4; ++n) {
          int kg = kb + n * 16 + fr;
#pragma unroll
          for (int j = 0; j < 4; ++j)
            if (kg > qg0 + fq * 4 + j) sa[b][n][j] = -1e30f;
        }
      }
      float corr[4];
#pragma unroll
      for (int j = 0; j < 4; ++j) {
        float v = fmaxf(fmaxf(sa[b][0][j], sa[b][1][j]), fmaxf(sa[b][2][j], sa[b][3][j]));
        v = rmax16(v);
        float mn = fmaxf(mrow[b][j], v);
        corr[j] = exp2f((mrow[b][j] - mn) * LOG2E);
        mrow[b][j] = mn;
      }
      float rs[4] = {0.f, 0.f, 0.f, 0.f};
#pragma unroll
      for (int n = 0; n < 4; ++n)
#pragma unroll
        for (int j = 0; j < 4; ++j) {
          float p = exp2f((sa[b][n][j] - mrow[b][j]) * LOG2E);
          sa[b][n][j] = p;
          rs[j] += p;
        }
#pragma unroll
      for (int j = 0; j < 4; ++j) lrow[b][j] = lrow[b][j] * corr[j] + rsum16(rs[j]);
#pragma unroll
      for (int nd = 0; nd < 8; ++nd)
#pragma unroll
        for (int j = 0; j < 4; ++j) o[b][nd][j] *= corr[j];
#pragma unroll
      for (int n = 0; n < 4; ++n)
#pragma unroll
        for (int j = 0; j < 4; ++j) {
          int q = bandq0 + b * 16 + fq * 4 + j;
          int byte = (q * 128 + (n * 16 + fr) * 2) ^ ((q & 7) << 4);
          *(u16*)((char*)Ps + byte) = f2bf(sa[b][n][j]);
        }
    }
    asm volatile("s_waitcnt lgkmcnt(0)" ::: "memory");
    __builtin_amdgcn_sched_barrier(0);

    bf16x8 pa[2][2];
#pragma unroll
    for (int b = 0; b < 2; ++b) {
      int prow = bandq0 + b * 16 + fr;
      int sw = (prow & 7) << 4;
#pragma unroll
      for (int t = 0; t < 2; ++t)
        pa[b][t] = *reinterpret_cast<const bf16x8*>((const char*)Ps +
                     ((prow * 128 + (t * 32 + fq * 8) * 2) ^ sw));
    }
    // O += P V : V frags read once, reused across both bands
#pragma unroll
    for (int nd = 0; nd < 8; ++nd) {
      const int dr = nd * 16 + fr;
      const int sw = (dr & 7) << 4;
      bf16x8 vf[2];
#pragma unroll
      for (int t = 0; t < 2; ++t)
        vf[t] = *reinterpret_cast<const bf16x8*>(Vc + ((dr * 128 + (t * 32 + fq * 8) * 2) ^ sw));
#pragma unroll
      for (int b = 0; b < 2; ++b)
#pragma unroll
        for (int t = 0; t < 2; ++t)
          o[b][nd] = __builtin_amdgcn_mfma_f32_16x16x32_bf16(pa[b][t], vf[t], o[b][nd], 0, 0, 0);
    }
    __syncthreads();  // drains vmcnt(0): next tile staged; buf safe to reuse
    buf ^= 1;
  }

  // epilogue: normalize and store AO[s][h*HD + d]
#pragma unroll
  for (int b = 0; b < 2; ++b)
#pragma unroll
    for (int j = 0; j < 4; ++j) {
      float inv = 1.0f / lrow[b][j];
      int s = qrow0 + bandq0 + b * 16 + fq * 4 + j;
#pragma unroll
      for (int nd = 0; nd < 8; ++nd)
        AO[(size_t)s * DMODEL + h * HD + nd * 16 + fr] = f2bf(o[b][nd][j] * inv);
    }
}

// ---------------- launch ----------------
extern "C" void kernel_launch(void* const* d_in, const int* in_sizes, int n_in,
                              void* d_out, int out_size, void* d_ws, size_t ws_size,
                              hipStream_t stream) {
  const float* hidden = (const float*)d_in[0];
  const float* Wq = (const float*)d_in[1];
  const float* Wk = (const float*)d_in[2];
  const float* Wv = (const float*)d_in[3];
  const float* Wo = (const float*)d_in[4];
  // d_in[5] = attention_mask: causal, applied analytically (unused)
  const int* pos_ids = (const int*)d_in[6];
  float* out = (float*)d_out;

  char* ws = (char*)d_ws;
  u16* Xb   = (u16*)(ws);                               // [4096][2048]   16MB
  u16* Wt   = (u16*)(ws + (16ull << 20));               // [3072][2048]   12MB
  u16* WoT  = (u16*)(ws + (28ull << 20));               // [2048][2048]    8MB
  u16* QKVb = (u16*)(ws + (36ull << 20));               // [4096][3072]   24MB
  u16* Qb   = (u16*)(ws + (60ull << 20));               // [16][4096][128] 16MB
  u16* Kb   = (u16*)(ws + (76ull << 20));               // [4][4096][128]   4MB
  u16* VT   = (u16*)(ws + (80ull << 20));               // [4][128][4096]   4MB
  u16* AO   = QKVb;  // alias: QKVb fully consumed before attention writes AO

  dim3 tb(32, 8);
  k_f32_to_bf16<<<dim3((S_LEN * DMODEL / 4) / 256), dim3(256), 0, stream>>>(
      hidden, Xb, S_LEN * DMODEL / 4);
  k_transpose_f32_bf16<<<dim3(64, 64), tb, 0, stream>>>(Wq, 2048, Wt, 2048);
  k_transpose_f32_bf16<<<dim3(16, 64), tb, 0, stream>>>(Wk, 512, Wt + (size_t)2048 * 2048, 2048);
  k_transpose_f32_bf16<<<dim3(16, 64), tb, 0, stream>>>(Wv, 512, Wt + (size_t)2560 * 2048, 2048);
  k_transpose_f32_bf16<<<dim3(64, 64), tb, 0, stream>>>(Wo, 2048, WoT, 2048);

  k_gemm_bt<1><<<dim3(24, 32), 256, 0, stream>>>(Xb, Wt, QKVb, S_LEN, NQKV, DMODEL);

  k_rope<<<dim3(S_LEN), 256, 0, stream>>>(QKVb, pos_ids, Qb, Kb);
  k_transpose_bf16<<<dim3(16, 128), tb, 0, stream>>>(QKVb + 2560, NQKV, VT, S_LEN);

  k_attn<<<dim3(NH, 32), 256, 0, stream>>>(Qb, Kb, VT, AO);

  k_gemm_bt<0><<<dim3(16, 32), 256, 0, stream>>>(AO, WoT, out, S_LEN, DMODEL, DMODEL);
}

// Round 3
// 324.759 us; speedup vs baseline: 1.8912x; 1.3335x over previous
//
#include <hip/hip_runtime.h>
#include <hip/hip_bf16.h>
#include <cstdint>
#include <cmath>

#define S_LEN 4096
#define DMODEL 2048
#define NH 16
#define NKV 4
#define HD 128
#define NQKV 3072  // 2048 Q + 512 K + 512 V

typedef unsigned short u16;
typedef __attribute__((ext_vector_type(8))) __bf16 bf16x8;
typedef __attribute__((ext_vector_type(4))) float f32x4;

__device__ __forceinline__ u16 f2bf(float f) {
  __bf16 h = (__bf16)f;  // RNE
  return __builtin_bit_cast(u16, h);
}
__device__ __forceinline__ float bf2f(u16 u) {
  return (float)__builtin_bit_cast(__bf16, u);
}

__device__ __forceinline__ void gload16(const void* g, void* l) {
  __builtin_amdgcn_global_load_lds(
      (const __attribute__((address_space(1))) void*)g,
      (__attribute__((address_space(3))) void*)l, 16, 0, 0);
}

// DPP rotation within 16-lane rows: VALU-only cross-lane reduce (no LDS pipe).
template <int CTRL>
__device__ __forceinline__ float dppf(float x) {
  int xi = __builtin_bit_cast(int, x);
  int r = __builtin_amdgcn_update_dpp(xi, xi, CTRL, 0xF, 0xF, true);
  return __builtin_bit_cast(float, r);
}
__device__ __forceinline__ float rmax16(float v) {
  v = fmaxf(v, dppf<0x128>(v));  // row_ror:8
  v = fmaxf(v, dppf<0x124>(v));  // row_ror:4
  v = fmaxf(v, dppf<0x122>(v));  // row_ror:2
  v = fmaxf(v, dppf<0x121>(v));  // row_ror:1
  return v;
}
__device__ __forceinline__ float rsum16(float v) {
  v += dppf<0x128>(v);
  v += dppf<0x124>(v);
  v += dppf<0x122>(v);
  v += dppf<0x121>(v);
  return v;
}

// ---------------- pack / convert ----------------
__global__ void k_f32_to_bf16(const float* __restrict__ src, u16* __restrict__ dst, int n4) {
  int i = blockIdx.x * blockDim.x + threadIdx.x;
  if (i < n4) {
    float4 v = reinterpret_cast<const float4*>(src)[i];
    ushort4 o = make_ushort4(f2bf(v.x), f2bf(v.y), f2bf(v.z), f2bf(v.w));
    reinterpret_cast<ushort4*>(dst)[i] = o;
  }
}

// dst[n][k] = bf16(src[k][n])
__global__ void k_transpose_f32_bf16(const float* __restrict__ src, int srcStride,
                                     u16* __restrict__ dst, int dstStride) {
  __shared__ float tile[32][33];
  int n0 = blockIdx.x * 32, k0 = blockIdx.y * 32;
  int tx = threadIdx.x, ty = threadIdx.y;  // 32 x 8
#pragma unroll
  for (int r = 0; r < 32; r += 8)
    tile[ty + r][tx] = src[(size_t)(k0 + ty + r) * srcStride + n0 + tx];
  __syncthreads();
#pragma unroll
  for (int r = 0; r < 32; r += 8)
    dst[(size_t)(n0 + ty + r) * dstStride + k0 + tx] = f2bf(tile[tx][ty + r]);
}

__global__ void k_transpose_bf16(const u16* __restrict__ src, int srcStride,
                                 u16* __restrict__ dst, int dstStride) {
  __shared__ u16 tile[32][33];
  int n0 = blockIdx.x * 32, k0 = blockIdx.y * 32;
  int tx = threadIdx.x, ty = threadIdx.y;  // 32 x 8
#pragma unroll
  for (int r = 0; r < 32; r += 8)
    tile[ty + r][tx] = src[(size_t)(k0 + ty + r) * srcStride + n0 + tx];
  __syncthreads();
#pragma unroll
  for (int r = 0; r < 32; r += 8)
    dst[(size_t)(n0 + ty + r) * dstStride + k0 + tx] = tile[tx][ty + r];
}

// ---------------- RoPE ----------------
// Q gets 1/sqrt(HD) * LOG2E folded in (softmax runs in exp2 domain).
__global__ void k_rope(const u16* __restrict__ qkv, const int* __restrict__ pos_ids,
                       u16* __restrict__ Qb, u16* __restrict__ Kb) {
  int s = blockIdx.x;
  float pos = (float)pos_ids[s];
  const u16* row = qkv + (size_t)s * NQKV;
  const float L2B = 13.287712379549449f;  // log2(10000)
  const float QSCALE = 0.08838834764831845f * 1.4426950408889634f;
  for (int c = threadIdx.x; c < DMODEL + NKV * HD; c += blockDim.x) {
    int d = c & 127;
    int dh = d & 63;
    float invf = exp2f(-(float)dh * (L2B / 64.0f));
    float ang = pos * invf;
    float cv = cosf(ang), sv = sinf(ang);
    float x = bf2f(row[c]);
    float xp = bf2f(row[c ^ 64]);
    float rot = (d < 64) ? -xp : xp;
    float out = x * cv + rot * sv;
    if (c < DMODEL) {
      int h = c >> 7;
      out *= QSCALE;
      Qb[((size_t)h * S_LEN + s) * HD + d] = f2bf(out);
    } else {
      int kvh = (c - DMODEL) >> 7;
      Kb[((size_t)kvh * S_LEN + s) * HD + d] = f2bf(out);
    }
  }
}

// ---------------- m97-style 128x128 GEMM, B^T operand ----------------
template <int OUT_BF16>
__global__ __launch_bounds__(256) void k_gemm_bt(const u16* __restrict__ A,
                                                 const u16* __restrict__ BT,
                                                 void* __restrict__ C, int M, int N, int K) {
  __shared__ __align__(16) u16 As[128 * 32];
  __shared__ __align__(16) u16 Bs[128 * 32];
  const int tid = threadIdx.x, wave = tid >> 6, lane = tid & 63;
  const int fr = lane & 15, fq = lane >> 4;
  const int rowBase = blockIdx.y * 128, colBase = blockIdx.x * 128;
  const int wr = wave >> 1, wc = wave & 1;
  f32x4 acc[4][4] = {};
  const int nk = K >> 5;
  for (int kt = 0; kt < nk; ++kt) {
    const int k0 = kt << 5;
#pragma unroll
    for (int p = 0; p < 2; ++p) {
      int cbase = p * 256 + wave * 64;
      int chunk = cbase + lane;
      int r = chunk >> 2, cb = chunk & 3;
      gload16(A + (size_t)(rowBase + r) * K + k0 + cb * 8, (char*)As + cbase * 16);
      gload16(BT + (size_t)(colBase + r) * K + k0 + cb * 8, (char*)Bs + cbase * 16);
    }
    __syncthreads();
    bf16x8 a[4], b[4];
#pragma unroll
    for (int m = 0; m < 4; ++m)
      a[m] = *reinterpret_cast<const bf16x8*>(&As[(wr * 64 + m * 16 + fr) * 32 + fq * 8]);
#pragma unroll
    for (int n = 0; n < 4; ++n)
      b[n] = *reinterpret_cast<const bf16x8*>(&Bs[(wc * 64 + n * 16 + fr) * 32 + fq * 8]);
#pragma unroll
    for (int m = 0; m < 4; ++m)
#pragma unroll
      for (int n = 0; n < 4; ++n)
        acc[m][n] = __builtin_amdgcn_mfma_f32_16x16x32_bf16(a[m], b[n], acc[m][n], 0, 0, 0);
    __syncthreads();
  }
#pragma unroll
  for (int m = 0; m < 4; ++m) {
    int row0 = rowBase + wr * 64 + m * 16 + fq * 4;
#pragma unroll
    for (int n = 0; n < 4; ++n) {
      int col = colBase + wc * 64 + n * 16 + fr;
#pragma unroll
      for (int j = 0; j < 4; ++j) {
        if (OUT_BF16)
          ((u16*)C)[(size_t)(row0 + j) * N + col] = f2bf(acc[m][n][j]);
        else
          ((float*)C)[(size_t)(row0 + j) * N + col] = acc[m][n][j];
      }
    }
  }
}

// ---------------- flash attention (causal, GQA) ----------------
// 8 waves x 16 q-rows (QBLK=128), KT=64, dbuf K/V, defer-max softmax.
// Each block serially does q-tiles {31-p, p}: exactly 66 steps per block ->
// 256 identical blocks = 1 per CU, zero tail imbalance.
// Qb [H][S][HD] (pre-scaled by 1/sqrt(HD)*LOG2E), Kb [KV][S][HD],
// VT [KV][HD][S], AO [S][H*HD]
__device__ __forceinline__ void stage_kv8(const u16* __restrict__ Kbk,
                                          const u16* __restrict__ VTk, int kb,
                                          char* KsB, char* VsB, int wave, int lane) {
#pragma unroll
  for (int p = 0; p < 2; ++p) {
    int cbase = p * 512 + wave * 64;
    int chunk = cbase + lane;
    int r = chunk >> 4, cb = chunk & 15;
    int cbs = cb ^ (r & 7);  // pre-swizzled source -> linear LDS dest (G21)
    gload16(Kbk + (size_t)(kb + r) * HD + cbs * 8, KsB + cbase * 16);
    int d = chunk >> 3, vb = chunk & 7;
    int vbs = vb ^ (d & 7);
    gload16(VTk + (size_t)d * S_LEN + kb + vbs * 8, VsB + cbase * 16);
  }
}

__global__ __launch_bounds__(512) void k_attn(const u16* __restrict__ Qb,
                                              const u16* __restrict__ Kb,
                                              const u16* __restrict__ VT,
                                              u16* __restrict__ AO) {
  __shared__ __align__(16) u16 Ks[2][64 * 128];  // [k][d], XOR-swizzled, dbuf
  __shared__ __align__(16) u16 Vs[2][128 * 64];  // [d][k], XOR-swizzled, dbuf
  __shared__ __align__(16) u16 Ps[128 * 64];     // [q][k], XOR-swizzled
  const int h = blockIdx.x;
  const int pairIdx = blockIdx.y;  // 0..15
  const int kv = h >> 2;
  const int tid = threadIdx.x, wave = tid >> 6, lane = tid & 63;
  const int fr = lane & 15, fq = lane >> 4;
  const float DEFER_THR = 11.541560327111707f;  // 8 * log2(e)

  const u16* Kbk = Kb + (size_t)kv * S_LEN * HD;
  const u16* VTk = VT + (size_t)kv * HD * S_LEN;

#pragma unroll 1
  for (int half = 0; half < 2; ++half) {
    const int qt = half ? pairIdx : (31 - pairIdx);
    const int qrow0 = qt * 128;
    const int bandq0 = wave * 16;

    int buf = 0;
    stage_kv8(Kbk, VTk, 0, (char*)Ks[0], (char*)Vs[0], wave, lane);

    bf16x8 qf[4];
    {
      const u16* qp = Qb + ((size_t)h * S_LEN + qrow0 + bandq0 + fr) * HD;
#pragma unroll
      for (int t = 0; t < 4; ++t)
        qf[t] = *reinterpret_cast<const bf16x8*>(qp + t * 32 + fq * 8);
    }
    f32x4 o[8] = {};
    float mrow[4], lrow[4];
#pragma unroll
    for (int j = 0; j < 4; ++j) { mrow[j] = -INFINITY; lrow[j] = 0.f; }

    __syncthreads();  // tile 0 staged

    const int nkt = 2 * qt + 2;
    for (int kt = 0; kt < nkt; ++kt) {
      if (kt + 1 < nkt)  // issue next tile's loads before computing current
        stage_kv8(Kbk, VTk, (kt + 1) * 64, (char*)Ks[buf ^ 1], (char*)Vs[buf ^ 1], wave, lane);
      const char* Kc = (const char*)Ks[buf];
      const char* Vc = (const char*)Vs[buf];
      const int kb = kt * 64;

      // S = Q K^T (16q x 64k per wave); scores already in exp2 domain
      f32x4 sa[4] = {};
#pragma unroll
      for (int n = 0; n < 4; ++n) {
        const int kr = n * 16 + fr;
        const int sw = (kr & 7) << 4;
#pragma unroll
        for (int t = 0; t < 4; ++t) {
          bf16x8 kf = *reinterpret_cast<const bf16x8*>(
              Kc + ((kr * 256 + (t * 32 + fq * 8) * 2) ^ sw));
          sa[n] = __builtin_amdgcn_mfma_f32_16x16x32_bf16(qf[t], kf, sa[n], 0, 0, 0);
        }
      }
      // causal mask (only near the diagonal)
      const int qg0 = qrow0 + bandq0;
      if (kb + 63 > qg0) {
#pragma unroll
        for (int n = 0; n < 4; ++n) {
          int kg = kb + n * 16 + fr;
#pragma unroll
          for (int j = 0; j < 4; ++j)
            if (kg > qg0 + fq * 4 + j) sa[n][j] = -1e30f;
        }
      }
      // row max (over n in-register, over fr-lanes via DPP)
      float tmax[4];
#pragma unroll
      for (int j = 0; j < 4; ++j) {
        float v = fmaxf(fmaxf(sa[0][j], sa[1][j]), fmaxf(sa[2][j], sa[3][j]));
        tmax[j] = rmax16(v);
      }
      // defer-max (T13): rescale only when the running max grows by > THR
      float over = fmaxf(fmaxf(tmax[0] - mrow[0], tmax[1] - mrow[1]),
                         fmaxf(tmax[2] - mrow[2], tmax[3] - mrow[3]));
      if (__any(over > DEFER_THR)) {
#pragma unroll
        for (int j = 0; j < 4; ++j) {
          float mn = fmaxf(mrow[j], tmax[j]);
          float corr = exp2f(mrow[j] - mn);
          mrow[j] = mn;
          lrow[j] *= corr;
#pragma unroll
          for (int nd = 0; nd < 8; ++nd) o[nd][j] *= corr;
        }
      }
      // P = exp2(S - m); row-sum
      float rs[4] = {0.f, 0.f, 0.f, 0.f};
#pragma unroll
      for (int n = 0; n < 4; ++n)
#pragma unroll
        for (int j = 0; j < 4; ++j) {
          float p = exp2f(sa[n][j] - mrow[j]);
          sa[n][j] = p;
          rs[j] += p;
        }
#pragma unroll
      for (int j = 0; j < 4; ++j) lrow[j] += rsum16(rs[j]);

      // P -> LDS (bf16, swizzled) -> PV A-operand
#pragma unroll
      for (int n = 0; n < 4; ++n)
#pragma unroll
        for (int j = 0; j < 4; ++j) {
          int q = bandq0 + fq * 4 + j;
          int byte = (q * 128 + (n * 16 + fr) * 2) ^ ((q & 7) << 4);
          *(u16*)((char*)Ps + byte) = f2bf(sa[n][j]);
        }
      asm volatile("s_waitcnt lgkmcnt(0)" ::: "memory");
      __builtin_amdgcn_sched_barrier(0);

      bf16x8 pa[2];
      {
        int prow = bandq0 + fr;
        int psw = (prow & 7) << 4;
#pragma unroll
        for (int t = 0; t < 2; ++t)
          pa[t] = *reinterpret_cast<const bf16x8*>(
              (const char*)Ps + ((prow * 128 + (t * 32 + fq * 8) * 2) ^ psw));
      }
      // O += P V
#pragma unroll
      for (int nd = 0; nd < 8; ++nd) {
        const int dr = nd * 16 + fr;
        const int sw = (dr & 7) << 4;
#pragma unroll
        for (int t = 0; t < 2; ++t) {
          bf16x8 vf = *reinterpret_cast<const bf16x8*>(
              Vc + ((dr * 128 + (t * 32 + fq * 8) * 2) ^ sw));
          o[nd] = __builtin_amdgcn_mfma_f32_16x16x32_bf16(pa[t], vf, o[nd], 0, 0, 0);
        }
      }
      __syncthreads();  // next tile staged; buf safe to flip
      buf ^= 1;
    }

    // epilogue: normalize and store AO[s][h*HD + d]
#pragma unroll
    for (int j = 0; j < 4; ++j) {
      float inv = 1.0f / lrow[j];
      int s = qrow0 + bandq0 + fq * 4 + j;
#pragma unroll
      for (int nd = 0; nd < 8; ++nd)
        AO[(size_t)s * DMODEL + h * HD + nd * 16 + fr] = f2bf(o[nd][j] * inv);
    }
    // all waves passed the final kt barrier; LDS free for next half
  }
}

// ---------------- launch ----------------
extern "C" void kernel_launch(void* const* d_in, const int* in_sizes, int n_in,
                              void* d_out, int out_size, void* d_ws, size_t ws_size,
                              hipStream_t stream) {
  const float* hidden = (const float*)d_in[0];
  const float* Wq = (const float*)d_in[1];
  const float* Wk = (const float*)d_in[2];
  const float* Wv = (const float*)d_in[3];
  const float* Wo = (const float*)d_in[4];
  // d_in[5] = attention_mask: causal, applied analytically (unused)
  const int* pos_ids = (const int*)d_in[6];
  float* out = (float*)d_out;

  char* ws = (char*)d_ws;
  u16* Xb   = (u16*)(ws);                               // [4096][2048]   16MB
  u16* Wt   = (u16*)(ws + (16ull << 20));               // [3072][2048]   12MB
  u16* WoT  = (u16*)(ws + (28ull << 20));               // [2048][2048]    8MB
  u16* QKVb = (u16*)(ws + (36ull << 20));               // [4096][3072]   24MB
  u16* Qb   = (u16*)(ws + (60ull << 20));               // [16][4096][128] 16MB
  u16* Kb   = (u16*)(ws + (76ull << 20));               // [4][4096][128]   4MB
  u16* VT   = (u16*)(ws + (80ull << 20));               // [4][128][4096]   4MB
  u16* AO   = QKVb;  // alias: QKVb fully consumed before attention writes AO

  dim3 tb(32, 8);
  k_f32_to_bf16<<<dim3((S_LEN * DMODEL / 4) / 256), dim3(256), 0, stream>>>(
      hidden, Xb, S_LEN * DMODEL / 4);
  k_transpose_f32_bf16<<<dim3(64, 64), tb, 0, stream>>>(Wq, 2048, Wt, 2048);
  k_transpose_f32_bf16<<<dim3(16, 64), tb, 0, stream>>>(Wk, 512, Wt + (size_t)2048 * 2048, 2048);
  k_transpose_f32_bf16<<<dim3(16, 64), tb, 0, stream>>>(Wv, 512, Wt + (size_t)2560 * 2048, 2048);
  k_transpose_f32_bf16<<<dim3(64, 64), tb, 0, stream>>>(Wo, 2048, WoT, 2048);

  k_gemm_bt<1><<<dim3(24, 32), 256, 0, stream>>>(Xb, Wt, QKVb, S_LEN, NQKV, DMODEL);

  k_rope<<<dim3(S_LEN), 256, 0, stream>>>(QKVb, pos_ids, Qb, Kb);
  k_transpose_bf16<<<dim3(16, 128), tb, 0, stream>>>(QKVb + 2560, NQKV, VT, S_LEN);

  k_attn<<<dim3(NH, 16), 512, 0, stream>>>(Qb, Kb, VT, AO);

  k_gemm_bt<0><<<dim3(16, 32), 256, 0, stream>>>(AO, WoT, out, S_LEN, DMODEL, DMODEL);
}